// Round 1
// baseline (3546.504 us; speedup 1.0000x reference)
//
#include <hip/hip_runtime.h>
#include <hip/hip_bf16.h>

#define N_NODES 100000
#define E_EDGES 1600000
#define IN_DIM  128
#define HID     64
#define HEADS   4
#define OUTC    16
#define NEG_SLOPE 0.2f
#define LN_EPS  1e-5f

// ---- order-preserving float<->uint mapping for atomicMax on floats ----
__device__ __forceinline__ unsigned enc_f(float f) {
    unsigned b = __float_as_uint(f);
    return (b & 0x80000000u) ? ~b : (b | 0x80000000u);
}
__device__ __forceinline__ float dec_f(unsigned k) {
    unsigned b = (k & 0x80000000u) ? (k & 0x7FFFFFFFu) : ~k;
    return __uint_as_float(b);
}

// ---- kernel A: h0 = relu(x @ Win + bin), one wave per node ----
__global__ void k_in_proj(const float* __restrict__ x, const float* __restrict__ W,
                          const float* __restrict__ bias, float* __restrict__ h) {
    __shared__ float Ws[IN_DIM * HID];   // 32 KB
    for (int i = threadIdx.x; i < IN_DIM * HID; i += blockDim.x) Ws[i] = W[i];
    __syncthreads();
    int lane = threadIdx.x & 63;
    int wid  = threadIdx.x >> 6;   // 0..3
    float b = bias[lane];
    for (int n = blockIdx.x * 4 + wid; n < N_NODES; n += gridDim.x * 4) {
        float x0 = x[n * IN_DIM + lane];
        float x1 = x[n * IN_DIM + 64 + lane];
        float acc = b;
        #pragma unroll
        for (int k = 0; k < 64; ++k) acc += __shfl(x0, k) * Ws[k * HID + lane];
        #pragma unroll
        for (int k = 0; k < 64; ++k) acc += __shfl(x1, k) * Ws[(k + 64) * HID + lane];
        h[n * HID + lane] = fmaxf(acc, 0.f);
    }
}

// ---- kernel B: hl = h @ Wg ; alpha_s/alpha_d per (node, head) ----
__global__ void k_gat_lin(const float* __restrict__ h, const float* __restrict__ W,
                          const float* __restrict__ as_w, const float* __restrict__ ad_w,
                          float* __restrict__ hl, float* __restrict__ as_o,
                          float* __restrict__ ad_o) {
    __shared__ float Ws[HID * HID];  // 16 KB
    __shared__ float As[64], Ad[64];
    for (int i = threadIdx.x; i < HID * HID; i += blockDim.x) Ws[i] = W[i];
    if (threadIdx.x < 64) { As[threadIdx.x] = as_w[threadIdx.x]; Ad[threadIdx.x] = ad_w[threadIdx.x]; }
    __syncthreads();
    int lane = threadIdx.x & 63;
    int wid  = threadIdx.x >> 6;
    int c = lane & 15, head = lane >> 4;
    for (int n = blockIdx.x * 4 + wid; n < N_NODES; n += gridDim.x * 4) {
        float hv = h[n * HID + lane];
        float acc = 0.f;
        #pragma unroll
        for (int k = 0; k < 64; ++k) acc += __shfl(hv, k) * Ws[k * HID + lane];
        hl[n * HID + lane] = acc;
        float s = acc * As[lane];
        float d = acc * Ad[lane];
        #pragma unroll
        for (int off = 1; off < 16; off <<= 1) {
            s += __shfl_xor(s, off);
            d += __shfl_xor(d, off);
        }
        if (c == 0) { as_o[n * HEADS + head] = s; ad_o[n * HEADS + head] = d; }
    }
}

// ---- kernel C: segment max of leakyrelu(as[src]+ad[dst]) over dst ----
__global__ void k_edge_max(const int* __restrict__ srcp, const int* __restrict__ dstp,
                           const float* __restrict__ as_, const float* __restrict__ ad_,
                           unsigned* __restrict__ mkey, int TE) {
    int i = blockIdx.x * blockDim.x + threadIdx.x;
    if (i >= TE) return;
    int s, d;
    if (i < E_EDGES) { s = srcp[i]; d = dstp[i]; } else { s = i - E_EDGES; d = s; }
    float4 a4 = *reinterpret_cast<const float4*>(as_ + s * 4);
    float4 b4 = *reinterpret_cast<const float4*>(ad_ + d * 4);
    float e0 = a4.x + b4.x, e1 = a4.y + b4.y, e2 = a4.z + b4.z, e3 = a4.w + b4.w;
    e0 = e0 > 0.f ? e0 : NEG_SLOPE * e0;
    e1 = e1 > 0.f ? e1 : NEG_SLOPE * e1;
    e2 = e2 > 0.f ? e2 : NEG_SLOPE * e2;
    e3 = e3 > 0.f ? e3 : NEG_SLOPE * e3;
    atomicMax(mkey + d * 4 + 0, enc_f(e0));
    atomicMax(mkey + d * 4 + 1, enc_f(e1));
    atomicMax(mkey + d * 4 + 2, enc_f(e2));
    atomicMax(mkey + d * 4 + 3, enc_f(e3));
}

// ---- kernel D: z[dst,h] = segment_sum exp(e - m[dst,h]) ----
__global__ void k_edge_sum(const int* __restrict__ srcp, const int* __restrict__ dstp,
                           const float* __restrict__ as_, const float* __restrict__ ad_,
                           const unsigned* __restrict__ mkey, float* __restrict__ z, int TE) {
    int i = blockIdx.x * blockDim.x + threadIdx.x;
    if (i >= TE) return;
    int s, d;
    if (i < E_EDGES) { s = srcp[i]; d = dstp[i]; } else { s = i - E_EDGES; d = s; }
    float4 a4 = *reinterpret_cast<const float4*>(as_ + s * 4);
    float4 b4 = *reinterpret_cast<const float4*>(ad_ + d * 4);
    float e[4] = {a4.x + b4.x, a4.y + b4.y, a4.z + b4.z, a4.w + b4.w};
    #pragma unroll
    for (int h = 0; h < 4; ++h) {
        float v = e[h] > 0.f ? e[h] : NEG_SLOPE * e[h];
        float m = dec_f(mkey[d * 4 + h]);
        atomicAdd(z + d * 4 + h, __expf(v - m));
    }
}

// ---- kernel E: message scatter, one wave (64 lanes) per edge ----
__global__ void k_edge_msg(const int* __restrict__ srcp, const int* __restrict__ dstp,
                           const float* __restrict__ as_, const float* __restrict__ ad_,
                           const unsigned* __restrict__ mkey, const float* __restrict__ z,
                           const float* __restrict__ hl, float* __restrict__ acc, int TE) {
    int gid = blockIdx.x * blockDim.x + threadIdx.x;
    int wid = gid >> 6, lane = gid & 63;
    if (wid >= TE) return;
    int s, d;
    if (wid < E_EDGES) { s = srcp[wid]; d = dstp[wid]; } else { s = wid - E_EDGES; d = s; }
    int head = lane >> 4;
    float e = as_[s * 4 + head] + ad_[d * 4 + head];
    e = e > 0.f ? e : NEG_SLOPE * e;
    float m = dec_f(mkey[d * 4 + head]);
    float zz = z[d * 4 + head];
    float alpha = __expf(e - m) / (zz + 1e-16f);
    atomicAdd(acc + d * 64 + lane, alpha * hl[s * 64 + lane]);
}

// ---- kernel F: epilogue: +bg, layernorm, relu, +residual ----
__global__ void k_epilogue(const float* __restrict__ acc, const float* __restrict__ bg,
                           const float* __restrict__ g, const float* __restrict__ b,
                           const float* __restrict__ hin, float* __restrict__ hout) {
    int gid = blockIdx.x * blockDim.x + threadIdx.x;
    int n = gid >> 6, lane = gid & 63;
    if (n >= N_NODES) return;
    float v = acc[n * 64 + lane] + bg[lane];
    float ssum = v;
    #pragma unroll
    for (int off = 1; off < 64; off <<= 1) ssum += __shfl_xor(ssum, off);
    float mu = ssum * (1.f / 64.f);
    float dv = v - mu;
    float vs = dv * dv;
    #pragma unroll
    for (int off = 1; off < 64; off <<= 1) vs += __shfl_xor(vs, off);
    float var = vs * (1.f / 64.f);
    float y = dv * rsqrtf(var + LN_EPS) * g[lane] + b[lane];
    y = fmaxf(y, 0.f) + hin[n * 64 + lane];
    hout[n * 64 + lane] = y;
}

// ---- kernel G: out = h @ Wout + bout ----
__global__ void k_out(const float* __restrict__ h, const float* __restrict__ Wout,
                      const float* __restrict__ bout, float* __restrict__ out) {
    int gid = blockIdx.x * blockDim.x + threadIdx.x;
    int n = gid >> 6, lane = gid & 63;
    if (n >= N_NODES) return;
    float p = h[n * 64 + lane] * Wout[lane];
    #pragma unroll
    for (int off = 1; off < 64; off <<= 1) p += __shfl_xor(p, off);
    if (lane == 0) out[n] = p + bout[0];
}

extern "C" void kernel_launch(void* const* d_in, const int* in_sizes, int n_in,
                              void* d_out, int out_size, void* d_ws, size_t ws_size,
                              hipStream_t stream) {
    const float* x     = (const float*)d_in[0];
    const int*   ei    = (const int*)  d_in[1];
    const float* Win   = (const float*)d_in[2];
    const float* bin_  = (const float*)d_in[3];
    const float* Wg    = (const float*)d_in[4];   // [3][64][64]
    const float* att_s = (const float*)d_in[5];   // [3][4][16]
    const float* att_d = (const float*)d_in[6];
    const float* bg    = (const float*)d_in[7];   // [3][64]
    const float* lng   = (const float*)d_in[8];
    const float* lnb   = (const float*)d_in[9];
    const float* Wout  = (const float*)d_in[10];
    const float* bout  = (const float*)d_in[11];
    float* out = (float*)d_out;

    float* B0   = (float*)d_ws;
    float* B1   = B0 + (size_t)N_NODES * 64;
    float* acc  = B1 + (size_t)N_NODES * 64;
    float* as_  = acc + (size_t)N_NODES * 64;
    float* ad_  = as_ + (size_t)N_NODES * 4;
    unsigned* mkey = (unsigned*)(ad_ + (size_t)N_NODES * 4);
    float* z    = (float*)(mkey + (size_t)N_NODES * 4);

    const int* srcp = ei;
    const int* dstp = ei + E_EDGES;
    const int TE = E_EDGES + N_NODES;

    k_in_proj<<<1024, 256, 0, stream>>>(x, Win, bin_, B0);

    float* hin = B0;
    float* hb  = B1;
    for (int L = 0; L < 3; ++L) {
        hipMemsetAsync(mkey, 0, (size_t)N_NODES * 4 * sizeof(unsigned), stream);
        hipMemsetAsync(z,    0, (size_t)N_NODES * 4 * sizeof(float), stream);
        hipMemsetAsync(acc,  0, (size_t)N_NODES * 64 * sizeof(float), stream);
        k_gat_lin<<<1024, 256, 0, stream>>>(hin, Wg + L * 64 * 64,
                                            att_s + L * 64, att_d + L * 64,
                                            hb, as_, ad_);
        k_edge_max<<<(TE + 255) / 256, 256, 0, stream>>>(srcp, dstp, as_, ad_, mkey, TE);
        k_edge_sum<<<(TE + 255) / 256, 256, 0, stream>>>(srcp, dstp, as_, ad_, mkey, z, TE);
        {
            long long threads = (long long)TE * 64;
            int blocks = (int)((threads + 255) / 256);
            k_edge_msg<<<blocks, 256, 0, stream>>>(srcp, dstp, as_, ad_, mkey, z, hb, acc, TE);
        }
        k_epilogue<<<(N_NODES * 64 + 255) / 256, 256, 0, stream>>>(
            acc, bg + L * 64, lng + L * 64, lnb + L * 64, hin, hb);
        float* t = hin; hin = hb; hb = t;
    }
    k_out<<<(N_NODES * 64 + 255) / 256, 256, 0, stream>>>(hin, Wout, bout, out);
}

// Round 2
// 1257.954 us; speedup vs baseline: 2.8193x; 2.8193x over previous
//
#include <hip/hip_runtime.h>
#include <hip/hip_bf16.h>

#define N_NODES 100000
#define E_EDGES 1600000
#define IN_DIM  128
#define HID     64
#define HEADS   4
#define NEG_SLOPE 0.2f
#define LN_EPS  1e-5f
#define NB_SCAN ((N_NODES + 255) / 256)   // 391

// ---- kernel A: h0 = relu(x @ Win + bin), one wave per node ----
__global__ void k_in_proj(const float* __restrict__ x, const float* __restrict__ W,
                          const float* __restrict__ bias, float* __restrict__ h) {
    __shared__ float Ws[IN_DIM * HID];   // 32 KB
    for (int i = threadIdx.x; i < IN_DIM * HID; i += blockDim.x) Ws[i] = W[i];
    __syncthreads();
    int lane = threadIdx.x & 63;
    int wid  = threadIdx.x >> 6;   // 0..3
    float b = bias[lane];
    for (int n = blockIdx.x * 4 + wid; n < N_NODES; n += gridDim.x * 4) {
        float x0 = x[n * IN_DIM + lane];
        float x1 = x[n * IN_DIM + 64 + lane];
        float acc = b;
        #pragma unroll
        for (int k = 0; k < 64; ++k) acc += __shfl(x0, k) * Ws[k * HID + lane];
        #pragma unroll
        for (int k = 0; k < 64; ++k) acc += __shfl(x1, k) * Ws[(k + 64) * HID + lane];
        h[n * HID + lane] = fmaxf(acc, 0.f);
    }
}

// ---- kernel B: hl = h @ Wg ; alpha_s/alpha_d per (node, head) ----
__global__ void k_gat_lin(const float* __restrict__ h, const float* __restrict__ W,
                          const float* __restrict__ as_w, const float* __restrict__ ad_w,
                          float* __restrict__ hl, float* __restrict__ as_o,
                          float* __restrict__ ad_o) {
    __shared__ float Ws[HID * HID];  // 16 KB
    __shared__ float As[64], Ad[64];
    for (int i = threadIdx.x; i < HID * HID; i += blockDim.x) Ws[i] = W[i];
    if (threadIdx.x < 64) { As[threadIdx.x] = as_w[threadIdx.x]; Ad[threadIdx.x] = ad_w[threadIdx.x]; }
    __syncthreads();
    int lane = threadIdx.x & 63;
    int wid  = threadIdx.x >> 6;
    int c = lane & 15, head = lane >> 4;
    for (int n = blockIdx.x * 4 + wid; n < N_NODES; n += gridDim.x * 4) {
        float hv = h[n * HID + lane];
        float acc = 0.f;
        #pragma unroll
        for (int k = 0; k < 64; ++k) acc += __shfl(hv, k) * Ws[k * HID + lane];
        hl[n * HID + lane] = acc;
        float s = acc * As[lane];
        float d = acc * Ad[lane];
        #pragma unroll
        for (int off = 1; off < 16; off <<= 1) {
            s += __shfl_xor(s, off);
            d += __shfl_xor(d, off);
        }
        if (c == 0) { as_o[n * HEADS + head] = s; ad_o[n * HEADS + head] = d; }
    }
}

// ---- CSR build: histogram -> 2-level exclusive scan -> scatter ----
__global__ void k_hist(const int* __restrict__ dstp, int* __restrict__ deg) {
    int i = blockIdx.x * blockDim.x + threadIdx.x;
    if (i < E_EDGES) atomicAdd(deg + dstp[i], 1);
}

__global__ void k_scan1(const int* __restrict__ deg, int* __restrict__ rowtmp,
                        int* __restrict__ bsum) {
    __shared__ int s[256];
    int i = blockIdx.x * 256 + threadIdx.x;
    int v = (i < N_NODES) ? deg[i] : 0;
    s[threadIdx.x] = v;
    __syncthreads();
    for (int off = 1; off < 256; off <<= 1) {
        int t = (threadIdx.x >= off) ? s[threadIdx.x - off] : 0;
        __syncthreads();
        s[threadIdx.x] += t;
        __syncthreads();
    }
    if (i < N_NODES) rowtmp[i] = s[threadIdx.x] - v;   // exclusive
    if (threadIdx.x == 255) bsum[blockIdx.x] = s[255];
}

__global__ void k_scan2(const int* __restrict__ bsum, int* __restrict__ bsumx) {
    __shared__ int s[512];
    int tid = threadIdx.x;
    int v = (tid < NB_SCAN) ? bsum[tid] : 0;
    s[tid] = v;
    __syncthreads();
    for (int off = 1; off < 512; off <<= 1) {
        int t = (tid >= off) ? s[tid - off] : 0;
        __syncthreads();
        s[tid] += t;
        __syncthreads();
    }
    bsumx[tid] = s[tid] - v;   // exclusive
}

__global__ void k_scan3(const int* __restrict__ rowtmp, const int* __restrict__ bsumx,
                        int* __restrict__ row, int* __restrict__ cur) {
    int i = blockIdx.x * 256 + threadIdx.x;
    if (i < N_NODES) {
        int r = rowtmp[i] + bsumx[i >> 8];
        row[i] = r;
        cur[i] = r;
    }
    if (i == 0) row[N_NODES] = E_EDGES;
}

__global__ void k_scatter(const int* __restrict__ srcp, const int* __restrict__ dstp,
                          int* __restrict__ cur, int* __restrict__ ssrc) {
    int i = blockIdx.x * blockDim.x + threadIdx.x;
    if (i >= E_EDGES) return;
    int d = dstp[i];
    int slot = atomicAdd(cur + d, 1);
    ssrc[slot] = srcp[i];
}

// ---- fused aggregation: softmax-weighted sum + bias + LN + ReLU + residual
//      (+ final projection on the last layer). One wave per dst node. ----
__global__ void k_gat_agg(const int* __restrict__ row, const int* __restrict__ ssrc,
                          const float* __restrict__ as_, const float* __restrict__ ad_,
                          const float* __restrict__ hl, const float* __restrict__ hres,
                          const float* __restrict__ bg, const float* __restrict__ g,
                          const float* __restrict__ b, float* __restrict__ hout,
                          const float* __restrict__ Wout, const float* __restrict__ bout,
                          float* __restrict__ out, int last) {
    int gid = blockIdx.x * blockDim.x + threadIdx.x;
    int n = gid >> 6, lane = gid & 63;
    if (n >= N_NODES) return;
    int head = lane >> 4;
    float adh = ad_[n * 4 + head];
    // self loop (s == n)
    float e = as_[n * 4 + head] + adh;
    e = e > 0.f ? e : NEG_SLOPE * e;
    float w = __expf(e);
    float accv = w * hl[n * 64 + lane];
    float z = w;
    int j1 = row[n + 1];
    for (int j = row[n]; j < j1; ++j) {
        int s = ssrc[j];
        float e2 = as_[s * 4 + head] + adh;
        e2 = e2 > 0.f ? e2 : NEG_SLOPE * e2;
        float w2 = __expf(e2);
        accv += w2 * hl[s * 64 + lane];
        z += w2;
    }
    float v = accv / (z + 1e-16f) + bg[lane];
    // LayerNorm over 64 lanes
    float ssum = v;
    #pragma unroll
    for (int off = 1; off < 64; off <<= 1) ssum += __shfl_xor(ssum, off);
    float mu = ssum * (1.f / 64.f);
    float dv = v - mu;
    float vs = dv * dv;
    #pragma unroll
    for (int off = 1; off < 64; off <<= 1) vs += __shfl_xor(vs, off);
    float var = vs * (1.f / 64.f);
    float y = dv * rsqrtf(var + LN_EPS) * g[lane] + b[lane];
    y = fmaxf(y, 0.f) + hres[n * 64 + lane];
    if (!last) {
        hout[n * 64 + lane] = y;
    } else {
        float p = y * Wout[lane];
        #pragma unroll
        for (int off = 1; off < 64; off <<= 1) p += __shfl_xor(p, off);
        if (lane == 0) out[n] = p + bout[0];
    }
}

extern "C" void kernel_launch(void* const* d_in, const int* in_sizes, int n_in,
                              void* d_out, int out_size, void* d_ws, size_t ws_size,
                              hipStream_t stream) {
    const float* x     = (const float*)d_in[0];
    const int*   ei    = (const int*)  d_in[1];
    const float* Win   = (const float*)d_in[2];
    const float* bin_  = (const float*)d_in[3];
    const float* Wg    = (const float*)d_in[4];   // [3][64][64]
    const float* att_s = (const float*)d_in[5];   // [3][4][16]
    const float* att_d = (const float*)d_in[6];
    const float* bg    = (const float*)d_in[7];   // [3][64]
    const float* lng   = (const float*)d_in[8];
    const float* lnb   = (const float*)d_in[9];
    const float* Wout  = (const float*)d_in[10];
    const float* bout  = (const float*)d_in[11];
    float* out = (float*)d_out;

    float* hA   = (float*)d_ws;                        // h (layer input / residual)
    float* hB   = hA + (size_t)N_NODES * 64;           // hl (transformed)
    float* hC   = hB + (size_t)N_NODES * 64;           // h (layer output)
    float* as_  = hC + (size_t)N_NODES * 64;
    float* ad_  = as_ + (size_t)N_NODES * 4;
    int* row    = (int*)(ad_ + (size_t)N_NODES * 4);   // N+1
    int* rowtmp = row + (N_NODES + 1);
    int* cur    = rowtmp + N_NODES;
    int* bsum   = cur + N_NODES;                       // 512
    int* bsumx  = bsum + 512;                          // 512
    int* deg    = bsumx + 512;                         // N
    int* ssrc   = deg + N_NODES;                       // E

    const int* srcp = ei;
    const int* dstp = ei + E_EDGES;

    // ---- CSR build (reused by all 3 layers) ----
    hipMemsetAsync(deg, 0, (size_t)N_NODES * sizeof(int), stream);
    k_hist<<<(E_EDGES + 255) / 256, 256, 0, stream>>>(dstp, deg);
    k_scan1<<<NB_SCAN, 256, 0, stream>>>(deg, rowtmp, bsum);
    k_scan2<<<1, 512, 0, stream>>>(bsum, bsumx);
    k_scan3<<<NB_SCAN, 256, 0, stream>>>(rowtmp, bsumx, row, cur);
    k_scatter<<<(E_EDGES + 255) / 256, 256, 0, stream>>>(srcp, dstp, cur, ssrc);

    k_in_proj<<<1024, 256, 0, stream>>>(x, Win, bin_, hA);

    const int aggBlocks = (N_NODES * 64 + 255) / 256;
    for (int L = 0; L < 3; ++L) {
        k_gat_lin<<<1024, 256, 0, stream>>>(hA, Wg + L * 64 * 64,
                                            att_s + L * 64, att_d + L * 64,
                                            hB, as_, ad_);
        k_gat_agg<<<aggBlocks, 256, 0, stream>>>(row, ssrc, as_, ad_, hB, hA,
                                                 bg + L * 64, lng + L * 64, lnb + L * 64,
                                                 hC, Wout, bout, out, (L == 2) ? 1 : 0);
        float* t = hA; hA = hC; hC = t;
    }
}

// Round 3
// 803.884 us; speedup vs baseline: 4.4117x; 1.5648x over previous
//
#include <hip/hip_runtime.h>
#include <hip/hip_bf16.h>

#define N_NODES 100000
#define E_EDGES 1600000
#define IN_DIM  128
#define HID     64
#define HEADS   4
#define NEG_SLOPE 0.2f
#define LN_EPS  1e-5f
#define NB_SCAN ((N_NODES + 255) / 256)   // 391

// ---- kernel A: h0 = relu(x @ Win + bin). Tiled GEMM, 32 nodes/block ----
__global__ __launch_bounds__(256) void k_in_proj(
        const float* __restrict__ x, const float* __restrict__ W,
        const float* __restrict__ bias, float* __restrict__ h) {
    __shared__ float Xs[32][132];     // padded: bank(4r+k), rows 16B-aligned (528B)
    __shared__ float Ws[128][64];     // 32 KB
    int t = threadIdx.x;
    const float4* W4 = (const float4*)W;
    float4* Ws4 = (float4*)&Ws[0][0];
    #pragma unroll
    for (int i = 0; i < 8; ++i) Ws4[t + 256 * i] = W4[t + 256 * i];
    int base = blockIdx.x * 32;
    const float4* X4 = (const float4*)(x + (size_t)base * IN_DIM);
    #pragma unroll
    for (int i = 0; i < 4; ++i) {
        int f = t + 256 * i;
        int row = f >> 5, col4 = f & 31;           // 32 float4 per row
        ((float4*)&Xs[row][0])[col4] = X4[f];
    }
    __syncthreads();
    int r = t >> 4;               // 0..15 -> rows {r, r+16}
    int c = (t & 15) * 4;         // cols c..c+3
    float4 bb = *(const float4*)(bias + c);
    float4 acc0 = bb, acc1 = bb;
    #pragma unroll 8
    for (int k = 0; k < 128; ++k) {
        float a0 = Xs[r][k];
        float a1 = Xs[r + 16][k];
        float4 b = *(const float4*)&Ws[k][c];
        acc0.x += a0 * b.x; acc0.y += a0 * b.y; acc0.z += a0 * b.z; acc0.w += a0 * b.w;
        acc1.x += a1 * b.x; acc1.y += a1 * b.y; acc1.z += a1 * b.z; acc1.w += a1 * b.w;
    }
    acc0.x = fmaxf(acc0.x, 0.f); acc0.y = fmaxf(acc0.y, 0.f);
    acc0.z = fmaxf(acc0.z, 0.f); acc0.w = fmaxf(acc0.w, 0.f);
    acc1.x = fmaxf(acc1.x, 0.f); acc1.y = fmaxf(acc1.y, 0.f);
    acc1.z = fmaxf(acc1.z, 0.f); acc1.w = fmaxf(acc1.w, 0.f);
    *(float4*)(h + (size_t)(base + r) * HID + c) = acc0;
    *(float4*)(h + (size_t)(base + r + 16) * HID + c) = acc1;
}

// ---- kernel B: hl = h @ Wg (no bias) + per-(node,head) alpha reductions ----
__global__ __launch_bounds__(256) void k_gat_lin(
        const float* __restrict__ h, const float* __restrict__ W,
        const float* __restrict__ as_w, const float* __restrict__ ad_w,
        float* __restrict__ hl, float* __restrict__ as_o, float* __restrict__ ad_o) {
    __shared__ float Xs[32][68];      // padded: bank(4r+k), rows 16B-aligned (272B)
    __shared__ float Ws[64][64];      // 16 KB
    int t = threadIdx.x;
    const float4* W4 = (const float4*)W;
    float4* Ws4 = (float4*)&Ws[0][0];
    #pragma unroll
    for (int i = 0; i < 4; ++i) Ws4[t + 256 * i] = W4[t + 256 * i];
    int base = blockIdx.x * 32;
    const float4* X4 = (const float4*)(h + (size_t)base * HID);
    #pragma unroll
    for (int i = 0; i < 2; ++i) {
        int f = t + 256 * i;
        int row = f >> 4, col4 = f & 15;           // 16 float4 per row
        ((float4*)&Xs[row][0])[col4] = X4[f];
    }
    __syncthreads();
    int r = t >> 4;
    int c = (t & 15) * 4;
    float4 acc0 = {0.f, 0.f, 0.f, 0.f}, acc1 = {0.f, 0.f, 0.f, 0.f};
    #pragma unroll 8
    for (int k = 0; k < 64; ++k) {
        float a0 = Xs[r][k];
        float a1 = Xs[r + 16][k];
        float4 b = *(const float4*)&Ws[k][c];
        acc0.x += a0 * b.x; acc0.y += a0 * b.y; acc0.z += a0 * b.z; acc0.w += a0 * b.w;
        acc1.x += a1 * b.x; acc1.y += a1 * b.y; acc1.z += a1 * b.z; acc1.w += a1 * b.w;
    }
    *(float4*)(hl + (size_t)(base + r) * HID + c) = acc0;
    *(float4*)(hl + (size_t)(base + r + 16) * HID + c) = acc1;
    // alpha: head = c/16, thread covers 4 of that head's 16 channels
    float4 A = *(const float4*)(as_w + c);
    float4 D = *(const float4*)(ad_w + c);
    float s0 = acc0.x * A.x + acc0.y * A.y + acc0.z * A.z + acc0.w * A.w;
    float d0 = acc0.x * D.x + acc0.y * D.y + acc0.z * D.z + acc0.w * D.w;
    float s1 = acc1.x * A.x + acc1.y * A.y + acc1.z * A.z + acc1.w * A.w;
    float d1 = acc1.x * D.x + acc1.y * D.y + acc1.z * D.z + acc1.w * D.w;
    #pragma unroll
    for (int off = 1; off < 4; off <<= 1) {
        s0 += __shfl_xor(s0, off); d0 += __shfl_xor(d0, off);
        s1 += __shfl_xor(s1, off); d1 += __shfl_xor(d1, off);
    }
    if ((t & 3) == 0) {
        int head = (t & 15) >> 2;
        as_o[(size_t)(base + r) * HEADS + head] = s0;
        ad_o[(size_t)(base + r) * HEADS + head] = d0;
        as_o[(size_t)(base + r + 16) * HEADS + head] = s1;
        ad_o[(size_t)(base + r + 16) * HEADS + head] = d1;
    }
}

// ---- CSR build: histogram -> 2-level exclusive scan -> scatter ----
__global__ void k_hist(const int* __restrict__ dstp, int* __restrict__ deg) {
    int i = blockIdx.x * blockDim.x + threadIdx.x;
    if (i < E_EDGES) atomicAdd(deg + dstp[i], 1);
}

__global__ void k_scan1(const int* __restrict__ deg, int* __restrict__ rowtmp,
                        int* __restrict__ bsum) {
    __shared__ int s[256];
    int i = blockIdx.x * 256 + threadIdx.x;
    int v = (i < N_NODES) ? deg[i] : 0;
    s[threadIdx.x] = v;
    __syncthreads();
    for (int off = 1; off < 256; off <<= 1) {
        int t = (threadIdx.x >= off) ? s[threadIdx.x - off] : 0;
        __syncthreads();
        s[threadIdx.x] += t;
        __syncthreads();
    }
    if (i < N_NODES) rowtmp[i] = s[threadIdx.x] - v;   // exclusive
    if (threadIdx.x == 255) bsum[blockIdx.x] = s[255];
}

__global__ void k_scan2(const int* __restrict__ bsum, int* __restrict__ bsumx) {
    __shared__ int s[512];
    int tid = threadIdx.x;
    int v = (tid < NB_SCAN) ? bsum[tid] : 0;
    s[tid] = v;
    __syncthreads();
    for (int off = 1; off < 512; off <<= 1) {
        int t = (tid >= off) ? s[tid - off] : 0;
        __syncthreads();
        s[tid] += t;
        __syncthreads();
    }
    bsumx[tid] = s[tid] - v;   // exclusive
}

__global__ void k_scan3(const int* __restrict__ rowtmp, const int* __restrict__ bsumx,
                        int* __restrict__ row, int* __restrict__ cur) {
    int i = blockIdx.x * 256 + threadIdx.x;
    if (i < N_NODES) {
        int r = rowtmp[i] + bsumx[i >> 8];
        row[i] = r;
        cur[i] = r;
    }
    if (i == 0) row[N_NODES] = E_EDGES;
}

__global__ void k_scatter(const int* __restrict__ srcp, const int* __restrict__ dstp,
                          int* __restrict__ cur, int* __restrict__ ssrc) {
    int i = blockIdx.x * blockDim.x + threadIdx.x;
    if (i >= E_EDGES) return;
    int d = dstp[i];
    int slot = atomicAdd(cur + d, 1);
    ssrc[slot] = srcp[i];
}

// ---- fused aggregation: softmax-weighted sum + bias + LN + ReLU + residual
//      (+ final projection on the last layer). One wave per dst node. ----
__global__ void k_gat_agg(const int* __restrict__ row, const int* __restrict__ ssrc,
                          const float* __restrict__ as_, const float* __restrict__ ad_,
                          const float* __restrict__ hl, const float* __restrict__ hres,
                          const float* __restrict__ bg, const float* __restrict__ g,
                          const float* __restrict__ b, float* __restrict__ hout,
                          const float* __restrict__ Wout, const float* __restrict__ bout,
                          float* __restrict__ out, int last) {
    int gid = blockIdx.x * blockDim.x + threadIdx.x;
    int n = gid >> 6, lane = gid & 63;
    if (n >= N_NODES) return;
    int head = lane >> 4;
    float adh = ad_[n * 4 + head];
    // self loop (s == n)
    float e = as_[n * 4 + head] + adh;
    e = e > 0.f ? e : NEG_SLOPE * e;
    float w = __expf(e);
    float accv = w * hl[(size_t)n * 64 + lane];
    float z = w;
    int j1 = row[n + 1];
    for (int j = row[n]; j < j1; ++j) {
        int s = ssrc[j];
        float e2 = as_[s * 4 + head] + adh;
        e2 = e2 > 0.f ? e2 : NEG_SLOPE * e2;
        float w2 = __expf(e2);
        accv += w2 * hl[(size_t)s * 64 + lane];
        z += w2;
    }
    float v = accv / (z + 1e-16f) + bg[lane];
    // LayerNorm over 64 lanes
    float ssum = v;
    #pragma unroll
    for (int off = 1; off < 64; off <<= 1) ssum += __shfl_xor(ssum, off);
    float mu = ssum * (1.f / 64.f);
    float dv = v - mu;
    float vs = dv * dv;
    #pragma unroll
    for (int off = 1; off < 64; off <<= 1) vs += __shfl_xor(vs, off);
    float var = vs * (1.f / 64.f);
    float y = dv * rsqrtf(var + LN_EPS) * g[lane] + b[lane];
    y = fmaxf(y, 0.f) + hres[(size_t)n * 64 + lane];
    if (!last) {
        hout[(size_t)n * 64 + lane] = y;
    } else {
        float p = y * Wout[lane];
        #pragma unroll
        for (int off = 1; off < 64; off <<= 1) p += __shfl_xor(p, off);
        if (lane == 0) out[n] = p + bout[0];
    }
}

extern "C" void kernel_launch(void* const* d_in, const int* in_sizes, int n_in,
                              void* d_out, int out_size, void* d_ws, size_t ws_size,
                              hipStream_t stream) {
    const float* x     = (const float*)d_in[0];
    const int*   ei    = (const int*)  d_in[1];
    const float* Win   = (const float*)d_in[2];
    const float* bin_  = (const float*)d_in[3];
    const float* Wg    = (const float*)d_in[4];   // [3][64][64]
    const float* att_s = (const float*)d_in[5];   // [3][4][16]
    const float* att_d = (const float*)d_in[6];
    const float* bg    = (const float*)d_in[7];   // [3][64]
    const float* lng   = (const float*)d_in[8];
    const float* lnb   = (const float*)d_in[9];
    const float* Wout  = (const float*)d_in[10];
    const float* bout  = (const float*)d_in[11];
    float* out = (float*)d_out;

    float* hA   = (float*)d_ws;                        // h (layer input / residual)
    float* hB   = hA + (size_t)N_NODES * 64;           // hl (transformed)
    float* hC   = hB + (size_t)N_NODES * 64;           // h (layer output)
    float* as_  = hC + (size_t)N_NODES * 64;
    float* ad_  = as_ + (size_t)N_NODES * 4;
    int* row    = (int*)(ad_ + (size_t)N_NODES * 4);   // N+1
    int* rowtmp = row + (N_NODES + 1);
    int* cur    = rowtmp + N_NODES;
    int* bsum   = cur + N_NODES;                       // 512
    int* bsumx  = bsum + 512;                          // 512
    int* deg    = bsumx + 512;                         // N
    int* ssrc   = deg + N_NODES;                       // E

    const int* srcp = ei;
    const int* dstp = ei + E_EDGES;

    // ---- CSR build (reused by all 3 layers) ----
    hipMemsetAsync(deg, 0, (size_t)N_NODES * sizeof(int), stream);
    k_hist<<<(E_EDGES + 255) / 256, 256, 0, stream>>>(dstp, deg);
    k_scan1<<<NB_SCAN, 256, 0, stream>>>(deg, rowtmp, bsum);
    k_scan2<<<1, 512, 0, stream>>>(bsum, bsumx);
    k_scan3<<<NB_SCAN, 256, 0, stream>>>(rowtmp, bsumx, row, cur);
    k_scatter<<<(E_EDGES + 255) / 256, 256, 0, stream>>>(srcp, dstp, cur, ssrc);

    k_in_proj<<<N_NODES / 32, 256, 0, stream>>>(x, Win, bin_, hA);

    const int aggBlocks = (N_NODES * 64 + 255) / 256;
    for (int L = 0; L < 3; ++L) {
        k_gat_lin<<<N_NODES / 32, 256, 0, stream>>>(hA, Wg + L * 64 * 64,
                                            att_s + L * 64, att_d + L * 64,
                                            hB, as_, ad_);
        k_gat_agg<<<aggBlocks, 256, 0, stream>>>(row, ssrc, as_, ad_, hB, hA,
                                                 bg + L * 64, lng + L * 64, lnb + L * 64,
                                                 hC, Wout, bout, out, (L == 2) ? 1 : 0);
        float* t = hA; hA = hC; hC = t;
    }
}

// Round 4
// 526.804 us; speedup vs baseline: 6.7321x; 1.5260x over previous
//
#include <hip/hip_runtime.h>
#include <hip/hip_bf16.h>

#define N_NODES 100000
#define E_EDGES 1600000
#define IN_DIM  128
#define HID     64
#define HEADS   4
#define NEG_SLOPE 0.2f
#define LN_EPS  1e-5f
#define NB_SCAN ((N_NODES + 255) / 256)   // 391

__device__ __forceinline__ float bflo(unsigned u) { return __uint_as_float(u << 16); }
__device__ __forceinline__ float bfhi(unsigned u) { return __uint_as_float(u & 0xffff0000u); }
__device__ __forceinline__ unsigned packbf2(float a, float b) {
    unsigned ua = __float_as_uint(a), ub = __float_as_uint(b);
    ua += 0x7fffu + ((ua >> 16) & 1u);
    ub += 0x7fffu + ((ub >> 16) & 1u);
    return (ua >> 16) | (ub & 0xffff0000u);
}

// ---- kernel A: h0 = relu(x @ Win + bin). Tiled GEMM, 32 nodes/block ----
__global__ __launch_bounds__(256) void k_in_proj(
        const float* __restrict__ x, const float* __restrict__ W,
        const float* __restrict__ bias, float* __restrict__ h) {
    __shared__ float Xs[32][132];
    __shared__ float Ws[128][64];
    int t = threadIdx.x;
    const float4* W4 = (const float4*)W;
    float4* Ws4 = (float4*)&Ws[0][0];
    #pragma unroll
    for (int i = 0; i < 8; ++i) Ws4[t + 256 * i] = W4[t + 256 * i];
    int base = blockIdx.x * 32;
    const float4* X4 = (const float4*)(x + (size_t)base * IN_DIM);
    #pragma unroll
    for (int i = 0; i < 4; ++i) {
        int f = t + 256 * i;
        int row = f >> 5, col4 = f & 31;
        ((float4*)&Xs[row][0])[col4] = X4[f];
    }
    __syncthreads();
    int r = t >> 4;
    int c = (t & 15) * 4;
    float4 bb = *(const float4*)(bias + c);
    float4 acc0 = bb, acc1 = bb;
    #pragma unroll 8
    for (int k = 0; k < 128; ++k) {
        float a0 = Xs[r][k];
        float a1 = Xs[r + 16][k];
        float4 b = *(const float4*)&Ws[k][c];
        acc0.x += a0 * b.x; acc0.y += a0 * b.y; acc0.z += a0 * b.z; acc0.w += a0 * b.w;
        acc1.x += a1 * b.x; acc1.y += a1 * b.y; acc1.z += a1 * b.z; acc1.w += a1 * b.w;
    }
    acc0.x = fmaxf(acc0.x, 0.f); acc0.y = fmaxf(acc0.y, 0.f);
    acc0.z = fmaxf(acc0.z, 0.f); acc0.w = fmaxf(acc0.w, 0.f);
    acc1.x = fmaxf(acc1.x, 0.f); acc1.y = fmaxf(acc1.y, 0.f);
    acc1.z = fmaxf(acc1.z, 0.f); acc1.w = fmaxf(acc1.w, 0.f);
    *(float4*)(h + (size_t)(base + r) * HID + c) = acc0;
    *(float4*)(h + (size_t)(base + r + 16) * HID + c) = acc1;
}

// ---- kernel B: hl(bf16) = h @ Wg + per-(node,head) alpha reductions ----
__global__ __launch_bounds__(256) void k_gat_lin(
        const float* __restrict__ h, const float* __restrict__ W,
        const float* __restrict__ as_w, const float* __restrict__ ad_w,
        unsigned* __restrict__ hlb, float* __restrict__ as_o, float* __restrict__ ad_o) {
    __shared__ float Xs[32][68];
    __shared__ float Ws[64][64];
    int t = threadIdx.x;
    const float4* W4 = (const float4*)W;
    float4* Ws4 = (float4*)&Ws[0][0];
    #pragma unroll
    for (int i = 0; i < 4; ++i) Ws4[t + 256 * i] = W4[t + 256 * i];
    int base = blockIdx.x * 32;
    const float4* X4 = (const float4*)(h + (size_t)base * HID);
    #pragma unroll
    for (int i = 0; i < 2; ++i) {
        int f = t + 256 * i;
        int row = f >> 4, col4 = f & 15;
        ((float4*)&Xs[row][0])[col4] = X4[f];
    }
    __syncthreads();
    int r = t >> 4;
    int c = (t & 15) * 4;
    float4 acc0 = {0.f, 0.f, 0.f, 0.f}, acc1 = {0.f, 0.f, 0.f, 0.f};
    #pragma unroll 8
    for (int k = 0; k < 64; ++k) {
        float a0 = Xs[r][k];
        float a1 = Xs[r + 16][k];
        float4 b = *(const float4*)&Ws[k][c];
        acc0.x += a0 * b.x; acc0.y += a0 * b.y; acc0.z += a0 * b.z; acc0.w += a0 * b.w;
        acc1.x += a1 * b.x; acc1.y += a1 * b.y; acc1.z += a1 * b.z; acc1.w += a1 * b.w;
    }
    uint2 p0, p1;
    p0.x = packbf2(acc0.x, acc0.y); p0.y = packbf2(acc0.z, acc0.w);
    p1.x = packbf2(acc1.x, acc1.y); p1.y = packbf2(acc1.z, acc1.w);
    ((uint2*)hlb)[(size_t)(base + r) * 16 + (c >> 2)] = p0;
    ((uint2*)hlb)[(size_t)(base + r + 16) * 16 + (c >> 2)] = p1;
    float4 A = *(const float4*)(as_w + c);
    float4 D = *(const float4*)(ad_w + c);
    float s0 = acc0.x * A.x + acc0.y * A.y + acc0.z * A.z + acc0.w * A.w;
    float d0 = acc0.x * D.x + acc0.y * D.y + acc0.z * D.z + acc0.w * D.w;
    float s1 = acc1.x * A.x + acc1.y * A.y + acc1.z * A.z + acc1.w * A.w;
    float d1 = acc1.x * D.x + acc1.y * D.y + acc1.z * D.z + acc1.w * D.w;
    #pragma unroll
    for (int off = 1; off < 4; off <<= 1) {
        s0 += __shfl_xor(s0, off); d0 += __shfl_xor(d0, off);
        s1 += __shfl_xor(s1, off); d1 += __shfl_xor(d1, off);
    }
    if ((t & 3) == 0) {
        int head = (t & 15) >> 2;
        as_o[(size_t)(base + r) * HEADS + head] = s0;
        ad_o[(size_t)(base + r) * HEADS + head] = d0;
        as_o[(size_t)(base + r + 16) * HEADS + head] = s1;
        ad_o[(size_t)(base + r + 16) * HEADS + head] = d1;
    }
}

// ---- CSR build ----
__global__ void k_hist(const int* __restrict__ dstp, int* __restrict__ deg) {
    int i = blockIdx.x * blockDim.x + threadIdx.x;
    if (i < E_EDGES) atomicAdd(deg + dstp[i], 1);
}

__global__ void k_scan1(const int* __restrict__ deg, int* __restrict__ rowtmp,
                        int* __restrict__ bsum) {
    __shared__ int s[256];
    int i = blockIdx.x * 256 + threadIdx.x;
    int v = (i < N_NODES) ? deg[i] : 0;
    s[threadIdx.x] = v;
    __syncthreads();
    for (int off = 1; off < 256; off <<= 1) {
        int t = (threadIdx.x >= off) ? s[threadIdx.x - off] : 0;
        __syncthreads();
        s[threadIdx.x] += t;
        __syncthreads();
    }
    if (i < N_NODES) rowtmp[i] = s[threadIdx.x] - v;
    if (threadIdx.x == 255) bsum[blockIdx.x] = s[255];
}

__global__ void k_scan2(const int* __restrict__ bsum, int* __restrict__ bsumx) {
    __shared__ int s[512];
    int tid = threadIdx.x;
    int v = (tid < NB_SCAN) ? bsum[tid] : 0;
    s[tid] = v;
    __syncthreads();
    for (int off = 1; off < 512; off <<= 1) {
        int t = (tid >= off) ? s[tid - off] : 0;
        __syncthreads();
        s[tid] += t;
        __syncthreads();
    }
    bsumx[tid] = s[tid] - v;
}

__global__ void k_scan3(const int* __restrict__ rowtmp, const int* __restrict__ bsumx,
                        int* __restrict__ row, int* __restrict__ cur) {
    int i = blockIdx.x * 256 + threadIdx.x;
    if (i < N_NODES) {
        int r = rowtmp[i] + bsumx[i >> 8];
        row[i] = r;
        cur[i] = r;
    }
    if (i == 0) row[N_NODES] = E_EDGES;
}

__global__ void k_scatter(const int* __restrict__ srcp, const int* __restrict__ dstp,
                          int* __restrict__ cur, int* __restrict__ ssrc) {
    int i = blockIdx.x * blockDim.x + threadIdx.x;
    if (i >= E_EDGES) return;
    int d = dstp[i];
    int slot = atomicAdd(cur + d, 1);
    ssrc[slot] = srcp[i];
}

// ---- fused aggregation: wave/node, 2 lane-halves x unroll2 = 4 edges in flight,
//      bf16 hl gather; + bias + LN + ReLU + residual (+ final proj on last) ----
__global__ __launch_bounds__(256) void k_gat_agg(
        const int* __restrict__ row, const int* __restrict__ ssrc,
        const float* __restrict__ as_, const float* __restrict__ ad_,
        const unsigned* __restrict__ hlb, const float* __restrict__ hres,
        const float* __restrict__ bg, const float* __restrict__ g,
        const float* __restrict__ b, float* __restrict__ hout,
        const float* __restrict__ Wout, const float* __restrict__ bout,
        float* __restrict__ out, int last) {
    int gid = blockIdx.x * blockDim.x + threadIdx.x;
    int n = gid >> 6;
    if (n >= N_NODES) return;
    int lane = threadIdx.x & 63;
    int half = lane >> 5, p = lane & 31;   // p -> channels 2p, 2p+1
    int head = p >> 3;
    float adh = ad_[n * 4 + head];
    float acc0 = 0.f, acc1 = 0.f, z = 0.f;
    if (half == 0) {   // self loop
        float e = as_[n * 4 + head] + adh;
        e = e > 0.f ? e : NEG_SLOPE * e;
        float w = __expf(e);
        unsigned u = hlb[(size_t)n * 32 + p];
        acc0 = w * bflo(u); acc1 = w * bfhi(u); z = w;
    }
    int j = row[n] + half;
    int jend = row[n + 1];
    for (; j + 2 < jend; j += 4) {
        int s0 = ssrc[j], s1 = ssrc[j + 2];
        float ea = as_[s0 * 4 + head] + adh;
        float eb = as_[s1 * 4 + head] + adh;
        ea = ea > 0.f ? ea : NEG_SLOPE * ea;
        eb = eb > 0.f ? eb : NEG_SLOPE * eb;
        float wa = __expf(ea), wb = __expf(eb);
        unsigned ua = hlb[(size_t)s0 * 32 + p];
        unsigned ub = hlb[(size_t)s1 * 32 + p];
        acc0 += wa * bflo(ua) + wb * bflo(ub);
        acc1 += wa * bfhi(ua) + wb * bfhi(ub);
        z += wa + wb;
    }
    if (j < jend) {
        int s0 = ssrc[j];
        float ea = as_[s0 * 4 + head] + adh;
        ea = ea > 0.f ? ea : NEG_SLOPE * ea;
        float wa = __expf(ea);
        unsigned ua = hlb[(size_t)s0 * 32 + p];
        acc0 += wa * bflo(ua);
        acc1 += wa * bfhi(ua);
        z += wa;
    }
    // merge halves (after this, both halves hold identical totals)
    acc0 += __shfl_xor(acc0, 32);
    acc1 += __shfl_xor(acc1, 32);
    z    += __shfl_xor(z, 32);
    float rz = 1.f / (z + 1e-16f);
    float2 bgv = ((const float2*)bg)[p];
    float v0 = acc0 * rz + bgv.x;
    float v1 = acc1 * rz + bgv.y;
    float ssum = v0 + v1;
    #pragma unroll
    for (int off = 1; off < 32; off <<= 1) ssum += __shfl_xor(ssum, off);
    float mu = ssum * (1.f / 64.f);
    float d0 = v0 - mu, d1 = v1 - mu;
    float vs = d0 * d0 + d1 * d1;
    #pragma unroll
    for (int off = 1; off < 32; off <<= 1) vs += __shfl_xor(vs, off);
    float rstd = rsqrtf(vs * (1.f / 64.f) + LN_EPS);
    float2 gv = ((const float2*)g)[p];
    float2 bv = ((const float2*)b)[p];
    float2 hr = ((const float2*)hres)[(size_t)n * 32 + p];
    float y0 = fmaxf(d0 * rstd * gv.x + bv.x, 0.f) + hr.x;
    float y1 = fmaxf(d1 * rstd * gv.y + bv.y, 0.f) + hr.y;
    if (!last) {
        if (half == 0) {
            float2 o; o.x = y0; o.y = y1;
            ((float2*)hout)[(size_t)n * 32 + p] = o;
        }
    } else {
        float2 wv = ((const float2*)Wout)[p];
        float pp = y0 * wv.x + y1 * wv.y;
        #pragma unroll
        for (int off = 1; off < 32; off <<= 1) pp += __shfl_xor(pp, off);
        if (lane == 0) out[n] = pp + bout[0];
    }
}

extern "C" void kernel_launch(void* const* d_in, const int* in_sizes, int n_in,
                              void* d_out, int out_size, void* d_ws, size_t ws_size,
                              hipStream_t stream) {
    const float* x     = (const float*)d_in[0];
    const int*   ei    = (const int*)  d_in[1];
    const float* Win   = (const float*)d_in[2];
    const float* bin_  = (const float*)d_in[3];
    const float* Wg    = (const float*)d_in[4];
    const float* att_s = (const float*)d_in[5];
    const float* att_d = (const float*)d_in[6];
    const float* bg    = (const float*)d_in[7];
    const float* lng   = (const float*)d_in[8];
    const float* lnb   = (const float*)d_in[9];
    const float* Wout  = (const float*)d_in[10];
    const float* bout  = (const float*)d_in[11];
    float* out = (float*)d_out;

    float* hA   = (float*)d_ws;                        // h (layer input / residual)
    float* hC   = hA + (size_t)N_NODES * 64;           // h (layer output)
    unsigned* hlb = (unsigned*)(hC + (size_t)N_NODES * 64);  // bf16x2 [N][32]
    float* as_  = (float*)(hlb + (size_t)N_NODES * 32);
    float* ad_  = as_ + (size_t)N_NODES * 4;
    int* row    = (int*)(ad_ + (size_t)N_NODES * 4);
    int* rowtmp = row + (N_NODES + 1);
    int* cur    = rowtmp + N_NODES;
    int* bsum   = cur + N_NODES;
    int* bsumx  = bsum + 512;
    int* deg    = bsumx + 512;
    int* ssrc   = deg + N_NODES;

    const int* srcp = ei;
    const int* dstp = ei + E_EDGES;

    hipMemsetAsync(deg, 0, (size_t)N_NODES * sizeof(int), stream);
    k_hist<<<(E_EDGES + 255) / 256, 256, 0, stream>>>(dstp, deg);
    k_scan1<<<NB_SCAN, 256, 0, stream>>>(deg, rowtmp, bsum);
    k_scan2<<<1, 512, 0, stream>>>(bsum, bsumx);
    k_scan3<<<NB_SCAN, 256, 0, stream>>>(rowtmp, bsumx, row, cur);
    k_scatter<<<(E_EDGES + 255) / 256, 256, 0, stream>>>(srcp, dstp, cur, ssrc);

    k_in_proj<<<N_NODES / 32, 256, 0, stream>>>(x, Win, bin_, hA);

    const int aggBlocks = (N_NODES * 64 + 255) / 256;
    for (int L = 0; L < 3; ++L) {
        k_gat_lin<<<N_NODES / 32, 256, 0, stream>>>(hA, Wg + L * 64 * 64,
                                            att_s + L * 64, att_d + L * 64,
                                            hlb, as_, ad_);
        k_gat_agg<<<aggBlocks, 256, 0, stream>>>(row, ssrc, as_, ad_, hlb, hA,
                                                 bg + L * 64, lng + L * 64, lnb + L * 64,
                                                 hC, Wout, bout, out, (L == 2) ? 1 : 0);
        float* t = hA; hA = hC; hC = t;
    }
}

// Round 5
// 396.161 us; speedup vs baseline: 8.9522x; 1.3298x over previous
//
#include <hip/hip_runtime.h>
#include <hip/hip_bf16.h>

#define N_NODES 100000
#define E_EDGES 1600000
#define IN_DIM  128
#define HID     64
#define HEADS   4
#define NEG_SLOPE 0.2f
#define LN_EPS  1e-5f

#define BUCK_SHIFT 7
#define NODES_PER_BUCK 128
#define NBUCK ((N_NODES + NODES_PER_BUCK - 1) / NODES_PER_BUCK)   // 782
#define NBUCK_PAD 1024
#define PART_CHUNK 4096

__device__ __forceinline__ float bflo(unsigned u) { return __uint_as_float(u << 16); }
__device__ __forceinline__ float bfhi(unsigned u) { return __uint_as_float(u & 0xffff0000u); }
__device__ __forceinline__ unsigned packbf2(float a, float b) {
    unsigned ua = __float_as_uint(a), ub = __float_as_uint(b);
    ua += 0x7fffu + ((ua >> 16) & 1u);
    ub += 0x7fffu + ((ub >> 16) & 1u);
    return (ua >> 16) | (ub & 0xffff0000u);
}

// ---- kernel A: h0 = relu(x @ Win + bin). Tiled GEMM, 32 nodes/block ----
__global__ __launch_bounds__(256) void k_in_proj(
        const float* __restrict__ x, const float* __restrict__ W,
        const float* __restrict__ bias, float* __restrict__ h) {
    __shared__ float Xs[32][132];
    __shared__ float Ws[128][64];
    int t = threadIdx.x;
    const float4* W4 = (const float4*)W;
    float4* Ws4 = (float4*)&Ws[0][0];
    #pragma unroll
    for (int i = 0; i < 8; ++i) Ws4[t + 256 * i] = W4[t + 256 * i];
    int base = blockIdx.x * 32;
    const float4* X4 = (const float4*)(x + (size_t)base * IN_DIM);
    #pragma unroll
    for (int i = 0; i < 4; ++i) {
        int f = t + 256 * i;
        int row = f >> 5, col4 = f & 31;
        ((float4*)&Xs[row][0])[col4] = X4[f];
    }
    __syncthreads();
    int r = t >> 4;
    int c = (t & 15) * 4;
    float4 bb = *(const float4*)(bias + c);
    float4 acc0 = bb, acc1 = bb;
    #pragma unroll 8
    for (int k = 0; k < 128; ++k) {
        float a0 = Xs[r][k];
        float a1 = Xs[r + 16][k];
        float4 b = *(const float4*)&Ws[k][c];
        acc0.x += a0 * b.x; acc0.y += a0 * b.y; acc0.z += a0 * b.z; acc0.w += a0 * b.w;
        acc1.x += a1 * b.x; acc1.y += a1 * b.y; acc1.z += a1 * b.z; acc1.w += a1 * b.w;
    }
    acc0.x = fmaxf(acc0.x, 0.f); acc0.y = fmaxf(acc0.y, 0.f);
    acc0.z = fmaxf(acc0.z, 0.f); acc0.w = fmaxf(acc0.w, 0.f);
    acc1.x = fmaxf(acc1.x, 0.f); acc1.y = fmaxf(acc1.y, 0.f);
    acc1.z = fmaxf(acc1.z, 0.f); acc1.w = fmaxf(acc1.w, 0.f);
    *(float4*)(h + (size_t)(base + r) * HID + c) = acc0;
    *(float4*)(h + (size_t)(base + r + 16) * HID + c) = acc1;
}

// ---- kernel B: hl(bf16) = h @ Wg + per-(node,head) alpha reductions ----
__global__ __launch_bounds__(256) void k_gat_lin(
        const float* __restrict__ h, const float* __restrict__ W,
        const float* __restrict__ as_w, const float* __restrict__ ad_w,
        unsigned* __restrict__ hlb, float* __restrict__ as_o, float* __restrict__ ad_o) {
    __shared__ float Xs[32][68];
    __shared__ float Ws[64][64];
    int t = threadIdx.x;
    const float4* W4 = (const float4*)W;
    float4* Ws4 = (float4*)&Ws[0][0];
    #pragma unroll
    for (int i = 0; i < 4; ++i) Ws4[t + 256 * i] = W4[t + 256 * i];
    int base = blockIdx.x * 32;
    const float4* X4 = (const float4*)(h + (size_t)base * HID);
    #pragma unroll
    for (int i = 0; i < 2; ++i) {
        int f = t + 256 * i;
        int row = f >> 4, col4 = f & 15;
        ((float4*)&Xs[row][0])[col4] = X4[f];
    }
    __syncthreads();
    int r = t >> 4;
    int c = (t & 15) * 4;
    float4 acc0 = {0.f, 0.f, 0.f, 0.f}, acc1 = {0.f, 0.f, 0.f, 0.f};
    #pragma unroll 8
    for (int k = 0; k < 64; ++k) {
        float a0 = Xs[r][k];
        float a1 = Xs[r + 16][k];
        float4 b = *(const float4*)&Ws[k][c];
        acc0.x += a0 * b.x; acc0.y += a0 * b.y; acc0.z += a0 * b.z; acc0.w += a0 * b.w;
        acc1.x += a1 * b.x; acc1.y += a1 * b.y; acc1.z += a1 * b.z; acc1.w += a1 * b.w;
    }
    uint2 p0, p1;
    p0.x = packbf2(acc0.x, acc0.y); p0.y = packbf2(acc0.z, acc0.w);
    p1.x = packbf2(acc1.x, acc1.y); p1.y = packbf2(acc1.z, acc1.w);
    ((uint2*)hlb)[(size_t)(base + r) * 16 + (c >> 2)] = p0;
    ((uint2*)hlb)[(size_t)(base + r + 16) * 16 + (c >> 2)] = p1;
    float4 A = *(const float4*)(as_w + c);
    float4 D = *(const float4*)(ad_w + c);
    float s0 = acc0.x * A.x + acc0.y * A.y + acc0.z * A.z + acc0.w * A.w;
    float d0 = acc0.x * D.x + acc0.y * D.y + acc0.z * D.z + acc0.w * D.w;
    float s1 = acc1.x * A.x + acc1.y * A.y + acc1.z * A.z + acc1.w * A.w;
    float d1 = acc1.x * D.x + acc1.y * D.y + acc1.z * D.z + acc1.w * D.w;
    #pragma unroll
    for (int off = 1; off < 4; off <<= 1) {
        s0 += __shfl_xor(s0, off); d0 += __shfl_xor(d0, off);
        s1 += __shfl_xor(s1, off); d1 += __shfl_xor(d1, off);
    }
    if ((t & 3) == 0) {
        int head = (t & 15) >> 2;
        as_o[(size_t)(base + r) * HEADS + head] = s0;
        ad_o[(size_t)(base + r) * HEADS + head] = d0;
        as_o[(size_t)(base + r + 16) * HEADS + head] = s1;
        ad_o[(size_t)(base + r + 16) * HEADS + head] = d1;
    }
}

// ---- CSR build, bucketized (bucket = dst >> 7 = 128 consecutive nodes) ----
__global__ __launch_bounds__(256) void k_bhist(const int* __restrict__ dstp,
                                               int* __restrict__ bcnt) {
    __shared__ int c[NBUCK_PAD];
    int t = threadIdx.x;
    for (int i = t; i < NBUCK_PAD; i += 256) c[i] = 0;
    __syncthreads();
    for (int i = blockIdx.x * 256 + t; i < E_EDGES; i += gridDim.x * 256)
        atomicAdd(&c[dstp[i] >> BUCK_SHIFT], 1);
    __syncthreads();
    for (int i = t; i < NBUCK_PAD; i += 256) {
        int v = c[i];
        if (v) atomicAdd(bcnt + i, v);
    }
}

__global__ __launch_bounds__(1024) void k_bscan(const int* __restrict__ bcnt,
                                                int* __restrict__ bbase,
                                                int* __restrict__ bcur) {
    __shared__ int s[NBUCK_PAD];
    int tid = threadIdx.x;
    int v = bcnt[tid];
    s[tid] = v;
    __syncthreads();
    for (int off = 1; off < NBUCK_PAD; off <<= 1) {
        int t = (tid >= off) ? s[tid - off] : 0;
        __syncthreads();
        s[tid] += t;
        __syncthreads();
    }
    int excl = s[tid] - v;
    bbase[tid] = excl;
    bcur[tid] = excl;
    if (tid == NBUCK_PAD - 1) bbase[NBUCK_PAD] = s[tid];
}

__global__ __launch_bounds__(256) void k_part(const int* __restrict__ srcp,
                                              const int* __restrict__ dstp,
                                              int* __restrict__ bcur,
                                              int2* __restrict__ ebuf) {
    __shared__ int cnt[NBUCK_PAD];
    __shared__ int gbase[NBUCK_PAD];
    int t = threadIdx.x;
    for (int i = t; i < NBUCK_PAD; i += 256) cnt[i] = 0;
    int e0 = blockIdx.x * PART_CHUNK;
    int e1 = min(e0 + PART_CHUNK, E_EDGES);
    __syncthreads();
    for (int i = e0 + t; i < e1; i += 256)
        atomicAdd(&cnt[dstp[i] >> BUCK_SHIFT], 1);
    __syncthreads();
    for (int b = t; b < NBUCK_PAD; b += 256) {
        int c = cnt[b];
        gbase[b] = c ? atomicAdd(bcur + b, c) : 0;
        cnt[b] = 0;
    }
    __syncthreads();
    for (int i = e0 + t; i < e1; i += 256) {
        int d = dstp[i];
        int b = d >> BUCK_SHIFT;
        int pos = gbase[b] + atomicAdd(&cnt[b], 1);
        ebuf[pos] = make_int2(srcp[i], d);
    }
}

__global__ __launch_bounds__(256) void k_fin(const int* __restrict__ bbase,
                                             const int2* __restrict__ ebuf,
                                             int* __restrict__ row,
                                             int* __restrict__ ssrc) {
    __shared__ int cnt[NODES_PER_BUCK];
    __shared__ int sc[NODES_PER_BUCK];
    __shared__ int rbase[NODES_PER_BUCK];
    int t = threadIdx.x;
    int b = blockIdx.x;
    int start = bbase[b], end = bbase[b + 1];
    int nb0 = b << BUCK_SHIFT;
    if (t < NODES_PER_BUCK) cnt[t] = 0;
    __syncthreads();
    for (int i = start + t; i < end; i += 256)
        atomicAdd(&cnt[ebuf[i].y - nb0], 1);
    __syncthreads();
    if (t < NODES_PER_BUCK) sc[t] = cnt[t];
    __syncthreads();
    for (int off = 1; off < NODES_PER_BUCK; off <<= 1) {
        int v = (t < NODES_PER_BUCK && t >= off) ? sc[t - off] : 0;
        __syncthreads();
        if (t < NODES_PER_BUCK) sc[t] += v;
        __syncthreads();
    }
    if (t < NODES_PER_BUCK) {
        int rb = start + sc[t] - cnt[t];
        rbase[t] = rb;
        int n = nb0 + t;
        if (n < N_NODES) row[n] = rb;
        cnt[t] = 0;
    }
    if (b == NBUCK - 1 && t == 0) row[N_NODES] = E_EDGES;
    __syncthreads();
    for (int i = start + t; i < end; i += 256) {
        int2 p = ebuf[i];
        int l = p.y - nb0;
        int slot = rbase[l] + atomicAdd(&cnt[l], 1);
        ssrc[slot] = p.x;
    }
}

// ---- fused aggregation: wave/node, 2 lane-halves x unroll2 = 4 edges in flight,
//      bf16 hl gather; + bias + LN + ReLU + residual (+ final proj on last) ----
__global__ __launch_bounds__(256) void k_gat_agg(
        const int* __restrict__ row, const int* __restrict__ ssrc,
        const float* __restrict__ as_, const float* __restrict__ ad_,
        const unsigned* __restrict__ hlb, const float* __restrict__ hres,
        const float* __restrict__ bg, const float* __restrict__ g,
        const float* __restrict__ b, float* __restrict__ hout,
        const float* __restrict__ Wout, const float* __restrict__ bout,
        float* __restrict__ out, int last) {
    int gid = blockIdx.x * blockDim.x + threadIdx.x;
    int n = gid >> 6;
    if (n >= N_NODES) return;
    int lane = threadIdx.x & 63;
    int half = lane >> 5, p = lane & 31;   // p -> channels 2p, 2p+1
    int head = p >> 3;
    float adh = ad_[n * 4 + head];
    float acc0 = 0.f, acc1 = 0.f, z = 0.f;
    if (half == 0) {   // self loop
        float e = as_[n * 4 + head] + adh;
        e = e > 0.f ? e : NEG_SLOPE * e;
        float w = __expf(e);
        unsigned u = hlb[(size_t)n * 32 + p];
        acc0 = w * bflo(u); acc1 = w * bfhi(u); z = w;
    }
    int j = row[n] + half;
    int jend = row[n + 1];
    for (; j + 2 < jend; j += 4) {
        int s0 = ssrc[j], s1 = ssrc[j + 2];
        float ea = as_[s0 * 4 + head] + adh;
        float eb = as_[s1 * 4 + head] + adh;
        ea = ea > 0.f ? ea : NEG_SLOPE * ea;
        eb = eb > 0.f ? eb : NEG_SLOPE * eb;
        float wa = __expf(ea), wb = __expf(eb);
        unsigned ua = hlb[(size_t)s0 * 32 + p];
        unsigned ub = hlb[(size_t)s1 * 32 + p];
        acc0 += wa * bflo(ua) + wb * bflo(ub);
        acc1 += wa * bfhi(ua) + wb * bfhi(ub);
        z += wa + wb;
    }
    if (j < jend) {
        int s0 = ssrc[j];
        float ea = as_[s0 * 4 + head] + adh;
        ea = ea > 0.f ? ea : NEG_SLOPE * ea;
        float wa = __expf(ea);
        unsigned ua = hlb[(size_t)s0 * 32 + p];
        acc0 += wa * bflo(ua);
        acc1 += wa * bfhi(ua);
        z += wa;
    }
    acc0 += __shfl_xor(acc0, 32);
    acc1 += __shfl_xor(acc1, 32);
    z    += __shfl_xor(z, 32);
    float rz = 1.f / (z + 1e-16f);
    float2 bgv = ((const float2*)bg)[p];
    float v0 = acc0 * rz + bgv.x;
    float v1 = acc1 * rz + bgv.y;
    float ssum = v0 + v1;
    #pragma unroll
    for (int off = 1; off < 32; off <<= 1) ssum += __shfl_xor(ssum, off);
    float mu = ssum * (1.f / 64.f);
    float d0 = v0 - mu, d1 = v1 - mu;
    float vs = d0 * d0 + d1 * d1;
    #pragma unroll
    for (int off = 1; off < 32; off <<= 1) vs += __shfl_xor(vs, off);
    float rstd = rsqrtf(vs * (1.f / 64.f) + LN_EPS);
    float2 gv = ((const float2*)g)[p];
    float2 bv = ((const float2*)b)[p];
    float2 hr = ((const float2*)hres)[(size_t)n * 32 + p];
    float y0 = fmaxf(d0 * rstd * gv.x + bv.x, 0.f) + hr.x;
    float y1 = fmaxf(d1 * rstd * gv.y + bv.y, 0.f) + hr.y;
    if (!last) {
        if (half == 0) {
            float2 o; o.x = y0; o.y = y1;
            ((float2*)hout)[(size_t)n * 32 + p] = o;
        }
    } else {
        float2 wv = ((const float2*)Wout)[p];
        float pp = y0 * wv.x + y1 * wv.y;
        #pragma unroll
        for (int off = 1; off < 32; off <<= 1) pp += __shfl_xor(pp, off);
        if (lane == 0) out[n] = pp + bout[0];
    }
}

extern "C" void kernel_launch(void* const* d_in, const int* in_sizes, int n_in,
                              void* d_out, int out_size, void* d_ws, size_t ws_size,
                              hipStream_t stream) {
    const float* x     = (const float*)d_in[0];
    const int*   ei    = (const int*)  d_in[1];
    const float* Win   = (const float*)d_in[2];
    const float* bin_  = (const float*)d_in[3];
    const float* Wg    = (const float*)d_in[4];
    const float* att_s = (const float*)d_in[5];
    const float* att_d = (const float*)d_in[6];
    const float* bg    = (const float*)d_in[7];
    const float* lng   = (const float*)d_in[8];
    const float* lnb   = (const float*)d_in[9];
    const float* Wout  = (const float*)d_in[10];
    const float* bout  = (const float*)d_in[11];
    float* out = (float*)d_out;

    float* hA   = (float*)d_ws;                        // h (layer input / residual)
    float* hC   = hA + (size_t)N_NODES * 64;           // h (layer output)
    unsigned* hlb = (unsigned*)(hC + (size_t)N_NODES * 64);  // bf16x2 [N][32]
    float* as_  = (float*)(hlb + (size_t)N_NODES * 32);
    float* ad_  = as_ + (size_t)N_NODES * 4;
    int* row    = (int*)(ad_ + (size_t)N_NODES * 4);   // N+1
    int* bcnt   = row + (N_NODES + 1);                 // 1024
    int* bbase  = bcnt + NBUCK_PAD;                    // 1025
    int* bcur   = bbase + (NBUCK_PAD + 1);             // 1024
    int* ssrc   = bcur + NBUCK_PAD;                    // E
    int2* ebuf  = (int2*)(ssrc + E_EDGES);             // E pairs

    const int* srcp = ei;
    const int* dstp = ei + E_EDGES;

    hipMemsetAsync(bcnt, 0, NBUCK_PAD * sizeof(int), stream);
    k_bhist<<<256, 256, 0, stream>>>(dstp, bcnt);
    k_bscan<<<1, NBUCK_PAD, 0, stream>>>(bcnt, bbase, bcur);
    k_part<<<(E_EDGES + PART_CHUNK - 1) / PART_CHUNK, 256, 0, stream>>>(srcp, dstp, bcur, ebuf);
    k_fin<<<NBUCK, 256, 0, stream>>>(bbase, ebuf, row, ssrc);

    k_in_proj<<<N_NODES / 32, 256, 0, stream>>>(x, Win, bin_, hA);

    const int aggBlocks = (N_NODES * 64 + 255) / 256;
    for (int L = 0; L < 3; ++L) {
        k_gat_lin<<<N_NODES / 32, 256, 0, stream>>>(hA, Wg + L * 64 * 64,
                                            att_s + L * 64, att_d + L * 64,
                                            hlb, as_, ad_);
        k_gat_agg<<<aggBlocks, 256, 0, stream>>>(row, ssrc, as_, ad_, hlb, hA,
                                                 bg + L * 64, lng + L * 64, lnb + L * 64,
                                                 hC, Wout, bout, out, (L == 2) ? 1 : 0);
        float* t = hA; hA = hC; hC = t;
    }
}

// Round 6
// 352.760 us; speedup vs baseline: 10.0536x; 1.1230x over previous
//
#include <hip/hip_runtime.h>
#include <hip/hip_bf16.h>

#define N_NODES 100000
#define E_EDGES 1600000
#define IN_DIM  128
#define HID     64
#define HEADS   4
#define NEG_SLOPE 0.2f
#define LN_EPS  1e-5f
#define LOG2E   1.4426950408889634f

#define BUCK_SHIFT 7
#define NODES_PER_BUCK 128
#define NBUCK ((N_NODES + NODES_PER_BUCK - 1) / NODES_PER_BUCK)   // 782
#define NBUCK_PAD 1024
#define PART_CHUNK 4096

__device__ __forceinline__ float bflo(unsigned u) { return __uint_as_float(u << 16); }
__device__ __forceinline__ float bfhi(unsigned u) { return __uint_as_float(u & 0xffff0000u); }
__device__ __forceinline__ unsigned packbf2(float a, float b) {
    unsigned ua = __float_as_uint(a), ub = __float_as_uint(b);
    ua += 0x7fffu + ((ua >> 16) & 1u);
    ub += 0x7fffu + ((ub >> 16) & 1u);
    return (ua >> 16) | (ub & 0xffff0000u);
}
// e pre-scaled by LOG2E; weight = exp(lrelu(e_orig)) = 2^(lrelu(e))
__device__ __forceinline__ float lrexp2(float e) {
    return __builtin_amdgcn_exp2f(fmaxf(e, NEG_SLOPE * e));
}

// ---- kernel A: h0 = relu(x @ Win + bin). Tiled GEMM, 32 nodes/block ----
__global__ __launch_bounds__(256) void k_in_proj(
        const float* __restrict__ x, const float* __restrict__ W,
        const float* __restrict__ bias, float* __restrict__ h) {
    __shared__ float Xs[32][132];
    __shared__ float Ws[128][64];
    int t = threadIdx.x;
    const float4* W4 = (const float4*)W;
    float4* Ws4 = (float4*)&Ws[0][0];
    #pragma unroll
    for (int i = 0; i < 8; ++i) Ws4[t + 256 * i] = W4[t + 256 * i];
    int base = blockIdx.x * 32;
    const float4* X4 = (const float4*)(x + (size_t)base * IN_DIM);
    #pragma unroll
    for (int i = 0; i < 4; ++i) {
        int f = t + 256 * i;
        int row = f >> 5, col4 = f & 31;
        ((float4*)&Xs[row][0])[col4] = X4[f];
    }
    __syncthreads();
    int r = t >> 4;
    int c = (t & 15) * 4;
    float4 bb = *(const float4*)(bias + c);
    float4 acc0 = bb, acc1 = bb;
    #pragma unroll 8
    for (int k = 0; k < 128; ++k) {
        float a0 = Xs[r][k];
        float a1 = Xs[r + 16][k];
        float4 b = *(const float4*)&Ws[k][c];
        acc0.x += a0 * b.x; acc0.y += a0 * b.y; acc0.z += a0 * b.z; acc0.w += a0 * b.w;
        acc1.x += a1 * b.x; acc1.y += a1 * b.y; acc1.z += a1 * b.z; acc1.w += a1 * b.w;
    }
    acc0.x = fmaxf(acc0.x, 0.f); acc0.y = fmaxf(acc0.y, 0.f);
    acc0.z = fmaxf(acc0.z, 0.f); acc0.w = fmaxf(acc0.w, 0.f);
    acc1.x = fmaxf(acc1.x, 0.f); acc1.y = fmaxf(acc1.y, 0.f);
    acc1.z = fmaxf(acc1.z, 0.f); acc1.w = fmaxf(acc1.w, 0.f);
    *(float4*)(h + (size_t)(base + r) * HID + c) = acc0;
    *(float4*)(h + (size_t)(base + r + 16) * HID + c) = acc1;
}

// ---- kernel B: hl(bf16) = h @ Wg + per-(node,head) alpha reductions
//      (alpha vectors pre-scaled by LOG2E for exp2 in agg) ----
__global__ __launch_bounds__(256) void k_gat_lin(
        const float* __restrict__ h, const float* __restrict__ W,
        const float* __restrict__ as_w, const float* __restrict__ ad_w,
        unsigned* __restrict__ hlb, float* __restrict__ as_o, float* __restrict__ ad_o) {
    __shared__ float Xs[32][68];
    __shared__ float Ws[64][64];
    int t = threadIdx.x;
    const float4* W4 = (const float4*)W;
    float4* Ws4 = (float4*)&Ws[0][0];
    #pragma unroll
    for (int i = 0; i < 4; ++i) Ws4[t + 256 * i] = W4[t + 256 * i];
    int base = blockIdx.x * 32;
    const float4* X4 = (const float4*)(h + (size_t)base * HID);
    #pragma unroll
    for (int i = 0; i < 2; ++i) {
        int f = t + 256 * i;
        int row = f >> 4, col4 = f & 15;
        ((float4*)&Xs[row][0])[col4] = X4[f];
    }
    __syncthreads();
    int r = t >> 4;
    int c = (t & 15) * 4;
    float4 acc0 = {0.f, 0.f, 0.f, 0.f}, acc1 = {0.f, 0.f, 0.f, 0.f};
    #pragma unroll 8
    for (int k = 0; k < 64; ++k) {
        float a0 = Xs[r][k];
        float a1 = Xs[r + 16][k];
        float4 b = *(const float4*)&Ws[k][c];
        acc0.x += a0 * b.x; acc0.y += a0 * b.y; acc0.z += a0 * b.z; acc0.w += a0 * b.w;
        acc1.x += a1 * b.x; acc1.y += a1 * b.y; acc1.z += a1 * b.z; acc1.w += a1 * b.w;
    }
    uint2 p0, p1;
    p0.x = packbf2(acc0.x, acc0.y); p0.y = packbf2(acc0.z, acc0.w);
    p1.x = packbf2(acc1.x, acc1.y); p1.y = packbf2(acc1.z, acc1.w);
    ((uint2*)hlb)[(size_t)(base + r) * 16 + (c >> 2)] = p0;
    ((uint2*)hlb)[(size_t)(base + r + 16) * 16 + (c >> 2)] = p1;
    float4 A = *(const float4*)(as_w + c);
    float4 D = *(const float4*)(ad_w + c);
    A.x *= LOG2E; A.y *= LOG2E; A.z *= LOG2E; A.w *= LOG2E;
    D.x *= LOG2E; D.y *= LOG2E; D.z *= LOG2E; D.w *= LOG2E;
    float s0 = acc0.x * A.x + acc0.y * A.y + acc0.z * A.z + acc0.w * A.w;
    float d0 = acc0.x * D.x + acc0.y * D.y + acc0.z * D.z + acc0.w * D.w;
    float s1 = acc1.x * A.x + acc1.y * A.y + acc1.z * A.z + acc1.w * A.w;
    float d1 = acc1.x * D.x + acc1.y * D.y + acc1.z * D.z + acc1.w * D.w;
    #pragma unroll
    for (int off = 1; off < 4; off <<= 1) {
        s0 += __shfl_xor(s0, off); d0 += __shfl_xor(d0, off);
        s1 += __shfl_xor(s1, off); d1 += __shfl_xor(d1, off);
    }
    if ((t & 3) == 0) {
        int head = (t & 15) >> 2;
        as_o[(size_t)(base + r) * HEADS + head] = s0;
        ad_o[(size_t)(base + r) * HEADS + head] = d0;
        as_o[(size_t)(base + r + 16) * HEADS + head] = s1;
        ad_o[(size_t)(base + r + 16) * HEADS + head] = d1;
    }
}

// ---- CSR build, bucketized (bucket = dst >> 7 = 128 consecutive nodes) ----
__global__ __launch_bounds__(256) void k_bhist(const int* __restrict__ dstp,
                                               int* __restrict__ bcnt) {
    __shared__ int c[NBUCK_PAD];
    int t = threadIdx.x;
    for (int i = t; i < NBUCK_PAD; i += 256) c[i] = 0;
    __syncthreads();
    for (int i = blockIdx.x * 256 + t; i < E_EDGES; i += gridDim.x * 256)
        atomicAdd(&c[dstp[i] >> BUCK_SHIFT], 1);
    __syncthreads();
    for (int i = t; i < NBUCK_PAD; i += 256) {
        int v = c[i];
        if (v) atomicAdd(bcnt + i, v);
    }
}

__global__ __launch_bounds__(1024) void k_bscan(const int* __restrict__ bcnt,
                                                int* __restrict__ bbase,
                                                int* __restrict__ bcur) {
    __shared__ int s[NBUCK_PAD];
    int tid = threadIdx.x;
    int v = bcnt[tid];
    s[tid] = v;
    __syncthreads();
    for (int off = 1; off < NBUCK_PAD; off <<= 1) {
        int t = (tid >= off) ? s[tid - off] : 0;
        __syncthreads();
        s[tid] += t;
        __syncthreads();
    }
    int excl = s[tid] - v;
    bbase[tid] = excl;
    bcur[tid] = excl;
    if (tid == NBUCK_PAD - 1) bbase[NBUCK_PAD] = s[tid];
}

__global__ __launch_bounds__(256) void k_part(const int* __restrict__ srcp,
                                              const int* __restrict__ dstp,
                                              int* __restrict__ bcur,
                                              int2* __restrict__ ebuf) {
    __shared__ int cnt[NBUCK_PAD];
    __shared__ int gbase[NBUCK_PAD];
    int t = threadIdx.x;
    for (int i = t; i < NBUCK_PAD; i += 256) cnt[i] = 0;
    int e0 = blockIdx.x * PART_CHUNK;
    int e1 = min(e0 + PART_CHUNK, E_EDGES);
    __syncthreads();
    for (int i = e0 + t; i < e1; i += 256)
        atomicAdd(&cnt[dstp[i] >> BUCK_SHIFT], 1);
    __syncthreads();
    for (int b = t; b < NBUCK_PAD; b += 256) {
        int c = cnt[b];
        gbase[b] = c ? atomicAdd(bcur + b, c) : 0;
        cnt[b] = 0;
    }
    __syncthreads();
    for (int i = e0 + t; i < e1; i += 256) {
        int d = dstp[i];
        int b = d >> BUCK_SHIFT;
        int pos = gbase[b] + atomicAdd(&cnt[b], 1);
        ebuf[pos] = make_int2(srcp[i], d);
    }
}

__global__ __launch_bounds__(256) void k_fin(const int* __restrict__ bbase,
                                             const int2* __restrict__ ebuf,
                                             int* __restrict__ row,
                                             int* __restrict__ ssrc) {
    __shared__ int cnt[NODES_PER_BUCK];
    __shared__ int sc[NODES_PER_BUCK];
    __shared__ int rbase[NODES_PER_BUCK];
    int t = threadIdx.x;
    int b = blockIdx.x;
    int start = bbase[b], end = bbase[b + 1];
    int nb0 = b << BUCK_SHIFT;
    if (t < NODES_PER_BUCK) cnt[t] = 0;
    __syncthreads();
    for (int i = start + t; i < end; i += 256)
        atomicAdd(&cnt[ebuf[i].y - nb0], 1);
    __syncthreads();
    if (t < NODES_PER_BUCK) sc[t] = cnt[t];
    __syncthreads();
    for (int off = 1; off < NODES_PER_BUCK; off <<= 1) {
        int v = (t < NODES_PER_BUCK && t >= off) ? sc[t - off] : 0;
        __syncthreads();
        if (t < NODES_PER_BUCK) sc[t] += v;
        __syncthreads();
    }
    if (t < NODES_PER_BUCK) {
        int rb = start + sc[t] - cnt[t];
        rbase[t] = rb;
        int n = nb0 + t;
        if (n < N_NODES) row[n] = rb;
        cnt[t] = 0;
    }
    if (b == NBUCK - 1 && t == 0) row[N_NODES] = E_EDGES;
    __syncthreads();
    for (int i = start + t; i < end; i += 256) {
        int2 p = ebuf[i];
        int l = p.y - nb0;
        int slot = rbase[l] + atomicAdd(&cnt[l], 1);
        ssrc[slot] = p.x;
    }
}

// ---- fused aggregation: wave/node, 4 groups x 16 lanes, uint2 loads,
//      unroll2 -> 8 edges in flight; + bias + LN + ReLU + residual
//      (+ final projection on last layer). ----
__global__ __launch_bounds__(256) void k_gat_agg(
        const int* __restrict__ row, const int* __restrict__ ssrc,
        const float* __restrict__ as_, const float* __restrict__ ad_,
        const unsigned* __restrict__ hlb, const float* __restrict__ hres,
        const float* __restrict__ bg, const float* __restrict__ g,
        const float* __restrict__ b, float* __restrict__ hout,
        const float* __restrict__ Wout, const float* __restrict__ bout,
        float* __restrict__ out, int last) {
    int gid = blockIdx.x * blockDim.x + threadIdx.x;
    int n = gid >> 6;
    if (n >= N_NODES) return;
    int lane = threadIdx.x & 63;
    int grp = lane >> 4;          // 0..3: edge group
    int q   = lane & 15;          // channels 4q..4q+3
    int head = q >> 2;
    const uint2* hlb2 = (const uint2*)hlb;
    float adh = ad_[n * 4 + head];
    float acc0 = 0.f, acc1 = 0.f, acc2 = 0.f, acc3 = 0.f, z = 0.f;
    if (grp == 0) {   // self loop
        float w = lrexp2(as_[n * 4 + head] + adh);
        uint2 u = hlb2[(size_t)n * 16 + q];
        acc0 = w * bflo(u.x); acc1 = w * bfhi(u.x);
        acc2 = w * bflo(u.y); acc3 = w * bfhi(u.y);
        z = w;
    }
    int j = row[n] + grp;
    int jend = row[n + 1];
    for (; j + 4 < jend; j += 8) {
        int s0 = ssrc[j], s1 = ssrc[j + 4];
        float wa = lrexp2(as_[s0 * 4 + head] + adh);
        float wb = lrexp2(as_[s1 * 4 + head] + adh);
        uint2 ua = hlb2[(size_t)s0 * 16 + q];
        uint2 ub = hlb2[(size_t)s1 * 16 + q];
        acc0 += wa * bflo(ua.x) + wb * bflo(ub.x);
        acc1 += wa * bfhi(ua.x) + wb * bfhi(ub.x);
        acc2 += wa * bflo(ua.y) + wb * bflo(ub.y);
        acc3 += wa * bfhi(ua.y) + wb * bfhi(ub.y);
        z += wa + wb;
    }
    if (j < jend) {
        int s0 = ssrc[j];
        float wa = lrexp2(as_[s0 * 4 + head] + adh);
        uint2 ua = hlb2[(size_t)s0 * 16 + q];
        acc0 += wa * bflo(ua.x);
        acc1 += wa * bfhi(ua.x);
        acc2 += wa * bflo(ua.y);
        acc3 += wa * bfhi(ua.y);
        z += wa;
    }
    // merge the 4 edge-groups (lanes with equal q)
    acc0 += __shfl_xor(acc0, 16); acc0 += __shfl_xor(acc0, 32);
    acc1 += __shfl_xor(acc1, 16); acc1 += __shfl_xor(acc1, 32);
    acc2 += __shfl_xor(acc2, 16); acc2 += __shfl_xor(acc2, 32);
    acc3 += __shfl_xor(acc3, 16); acc3 += __shfl_xor(acc3, 32);
    z    += __shfl_xor(z, 16);    z    += __shfl_xor(z, 32);
    float rz = 1.f / (z + 1e-16f);
    float4 bgv = ((const float4*)bg)[q];
    float v0 = acc0 * rz + bgv.x;
    float v1 = acc1 * rz + bgv.y;
    float v2 = acc2 * rz + bgv.z;
    float v3 = acc3 * rz + bgv.w;
    float ssum = v0 + v1 + v2 + v3;
    #pragma unroll
    for (int off = 1; off < 16; off <<= 1) ssum += __shfl_xor(ssum, off);
    float mu = ssum * (1.f / 64.f);
    float d0 = v0 - mu, d1 = v1 - mu, d2 = v2 - mu, d3 = v3 - mu;
    float vs = d0 * d0 + d1 * d1 + d2 * d2 + d3 * d3;
    #pragma unroll
    for (int off = 1; off < 16; off <<= 1) vs += __shfl_xor(vs, off);
    float rstd = rsqrtf(vs * (1.f / 64.f) + LN_EPS);
    float4 gv = ((const float4*)g)[q];
    float4 bv = ((const float4*)b)[q];
    float4 hr = ((const float4*)hres)[(size_t)n * 16 + q];
    float y0 = fmaxf(d0 * rstd * gv.x + bv.x, 0.f) + hr.x;
    float y1 = fmaxf(d1 * rstd * gv.y + bv.y, 0.f) + hr.y;
    float y2 = fmaxf(d2 * rstd * gv.z + bv.z, 0.f) + hr.z;
    float y3 = fmaxf(d3 * rstd * gv.w + bv.w, 0.f) + hr.w;
    if (!last) {
        if (grp == 0) {
            float4 o; o.x = y0; o.y = y1; o.z = y2; o.w = y3;
            ((float4*)hout)[(size_t)n * 16 + q] = o;
        }
    } else {
        float4 wv = ((const float4*)Wout)[q];
        float pp = y0 * wv.x + y1 * wv.y + y2 * wv.z + y3 * wv.w;
        #pragma unroll
        for (int off = 1; off < 16; off <<= 1) pp += __shfl_xor(pp, off);
        if (lane == 0) out[n] = pp + bout[0];
    }
}

extern "C" void kernel_launch(void* const* d_in, const int* in_sizes, int n_in,
                              void* d_out, int out_size, void* d_ws, size_t ws_size,
                              hipStream_t stream) {
    const float* x     = (const float*)d_in[0];
    const int*   ei    = (const int*)  d_in[1];
    const float* Win   = (const float*)d_in[2];
    const float* bin_  = (const float*)d_in[3];
    const float* Wg    = (const float*)d_in[4];
    const float* att_s = (const float*)d_in[5];
    const float* att_d = (const float*)d_in[6];
    const float* bg    = (const float*)d_in[7];
    const float* lng   = (const float*)d_in[8];
    const float* lnb   = (const float*)d_in[9];
    const float* Wout  = (const float*)d_in[10];
    const float* bout  = (const float*)d_in[11];
    float* out = (float*)d_out;

    float* hA   = (float*)d_ws;                        // h (layer input / residual)
    float* hC   = hA + (size_t)N_NODES * 64;           // h (layer output)
    unsigned* hlb = (unsigned*)(hC + (size_t)N_NODES * 64);  // bf16x2 [N][32]
    float* as_  = (float*)(hlb + (size_t)N_NODES * 32);
    float* ad_  = as_ + (size_t)N_NODES * 4;
    int* row    = (int*)(ad_ + (size_t)N_NODES * 4);   // N+1
    int* bcnt   = row + (N_NODES + 1);                 // 1024
    int* bbase  = bcnt + NBUCK_PAD;                    // 1025
    int* bcur   = bbase + (NBUCK_PAD + 1);             // 1024
    int* ssrc   = bcur + NBUCK_PAD;                    // E
    int2* ebuf  = (int2*)(ssrc + E_EDGES);             // E pairs

    const int* srcp = ei;
    const int* dstp = ei + E_EDGES;

    hipMemsetAsync(bcnt, 0, NBUCK_PAD * sizeof(int), stream);
    k_bhist<<<256, 256, 0, stream>>>(dstp, bcnt);
    k_bscan<<<1, NBUCK_PAD, 0, stream>>>(bcnt, bbase, bcur);
    k_part<<<(E_EDGES + PART_CHUNK - 1) / PART_CHUNK, 256, 0, stream>>>(srcp, dstp, bcur, ebuf);
    k_fin<<<NBUCK, 256, 0, stream>>>(bbase, ebuf, row, ssrc);

    k_in_proj<<<N_NODES / 32, 256, 0, stream>>>(x, Win, bin_, hA);

    const int aggBlocks = (N_NODES * 64 + 255) / 256;
    for (int L = 0; L < 3; ++L) {
        k_gat_lin<<<N_NODES / 32, 256, 0, stream>>>(hA, Wg + L * 64 * 64,
                                            att_s + L * 64, att_d + L * 64,
                                            hlb, as_, ad_);
        k_gat_agg<<<aggBlocks, 256, 0, stream>>>(row, ssrc, as_, ad_, hlb, hA,
                                                 bg + L * 64, lng + L * 64, lnb + L * 64,
                                                 hC, Wout, bout, out, (L == 2) ? 1 : 0);
        float* t = hA; hA = hC; hC = t;
    }
}